// Round 8
// baseline (204.842 us; speedup 1.0000x reference)
//
#include <hip/hip_runtime.h>

#define NSTEPS 730
#define NGRID  10000
#define LENF   15
#define NEARZERO 1e-5f
#define KB 10            // steps per pipeline block
#define NBLK 73          // 730 = 73 * 10
#define NROUND (NBLK + 4)

struct F3 { float p, t, e; };  // (prcp, tmean, pet), 12B

// ---- fast ALU-only pow pieces (replaces v_log_f32/v_exp_f32 on the soil
// chain: those have ~30cy dependent latency; these are 4cy full-rate ops) ----
// Returns log2(x) + 127  (exponent bias NOT removed; caller folds -127*BETA
// into its precomputed constant). Quartic mantissa fit, |err| <= 4.4e-4.
__device__ __forceinline__ float fast_log2_b(float x) {
    int   i = __float_as_int(x);                       // x > 0 always (>=NEARZERO)
    float m = __int_as_float((i & 0x007FFFFF) | 0x3F800000);  // [1,2)
    float f = m - 1.0f;
    float e = (float)(i >> 23);                        // biased exponent
    float q = fmaf(f, -0.1032747f, 0.3591929f);        // log2(1+f) ~= f*q(f)
    q = fmaf(f, q, -0.6981612f);
    q = fmaf(f, q, 1.4418100f);
    return fmaf(f, q, e);
}
// 2^y for y in [-200, 16]; floor-split + cubic frac poly (rel err <= 2.3e-4);
// v_ldexp_f32 handles deep-negative exponents (underflow to 0) exactly.
__device__ __forceinline__ float fast_exp2(float y) {
    float fl  = floorf(y);
    float f   = y - fl;
    float psi = fmaf(f, 0.0728185f, 0.233449f);
    psi = fmaf(f, psi, 0.693498f);
    float p = fmaf(f, psi, 1.0f);
    return __builtin_ldexpf(p, (int)fl);
}

// 3-role software pipeline (round-7 skeleton, PASSED at 105us) with the soil
// chain's four dependent HW transcendentals replaced by full-rate ALU
// approximations. Evidence: round 6 (fused) and round 7 (3-role) both sit at
// ~330-380 cy/step; round 7's B-wave issues only ~100cy/step (VALUBusy 13.7%
// x 1024/471 ~= 30% per busy SIMD) -> ~200cy/step of pure dependency stall,
// matching 4 x ~30cy-latency v_log/v_exp on the carried sm-cycle. The ALU
// pow keeps issue ~same but cuts chain to ~155cy/step.
__global__ __launch_bounds__(192, 1) void hbv_pipe3(const float* __restrict__ xp,
                                                    const float* __restrict__ ps,
                                                    float* __restrict__ out) {
    __shared__ float2 rtpe_buf[2][KB][64];  // A -> B : (rain+tosoil, pet)
    __shared__ float  q_buf[2][KB][64];     // B -> C : q

    const int lane = threadIdx.x & 63;
    const int wid  = threadIdx.x >> 6;
    int g = blockIdx.x * 64 + lane;
    g = (g < NGRID) ? g : (NGRID - 1);      // clamp: dup work, benign
    const int pb = g * 16;
    const F3* __restrict__ xv = (const F3*)xp;

    // ---- role A state ----
    float aTT = 0, aCFMAX = 0, aCFRxCFMAX = 0, aCWH = 0;
    float snow = NEARZERO, melt = NEARZERO;
    F3 abufA[KB], abufB[KB];               // static names only (no runtime idx)
    // ---- role B state ----
    float bFC = 0, bBETA = 0, bB1p = 0, bBETAET = 0, bB2p = 0, bInvFC = 0,
          bC = 0, bPERC = 0, bK0 = 0, bK1 = 0, bK2 = 0, bUZL = 0;
    float sm = NEARZERO, suz = NEARZERO, slz = NEARZERO;
    // ---- role C state ----
    float w[LENF];
    float r[LENF - 1];
    float outv[KB];

    if (wid == 0) {
        aTT        = ps[pb + 8]  * 5.0f - 2.5f;
        aCFMAX     = ps[pb + 9]  * 9.5f + 0.5f;
        aCFRxCFMAX = (ps[pb + 10] * 0.1f) * aCFMAX;
        aCWH       = ps[pb + 11] * 0.2f;
    } else if (wid == 1) {
        bFC     = ps[pb + 1]  * 950.0f + 50.0f;
        bBETA   = ps[pb + 0]  * 5.0f   + 1.0f;
        float LP = ps[pb + 5] * 0.8f   + 0.2f;
        bBETAET = ps[pb + 12] * 4.7f   + 0.3f;
        bInvFC  = 1.0f / bFC;
        // y = BETA*(log2(sm)-log2(FC)); fast_log2_b returns log2(sm)+127, so
        // fold -(log2(FC)+127)*BETA into the constant (HW log2 here: one-time)
        bB1p = -bBETA   * (__builtin_amdgcn_logf(bFC) + 127.0f);
        bB2p = -bBETAET * (__builtin_amdgcn_logf(LP * bFC) + 127.0f);
        bC   = ps[pb + 13];
        bPERC = ps[pb + 6] * 10.0f;
        bK0  = ps[pb + 2] * 0.85f  + 0.05f;
        bK1  = ps[pb + 3] * 0.49f  + 0.01f;
        bK2  = ps[pb + 4] * 0.199f + 0.001f;
        bUZL = ps[pb + 7] * 100.0f;
    } else {
        // routing weights; -lgamma(aa)-aa*log(theta) cancel under normalization
        const float LOG2E = 1.4426950408889634f;
        float aa    = fmaxf(ps[pb + 14] * 2.9f, 0.0f) + 0.1f;
        float theta = fmaxf(ps[pb + 15] * 6.5f, 0.0f) + 0.5f;
        float sc = LOG2E / theta, am1 = aa - 1.0f, wsum = 0.0f;
#pragma unroll
        for (int k = 0; k < LENF; ++k) {
            float tg = (float)k + 0.5f;
            w[k] = __builtin_amdgcn_exp2f(am1 * __builtin_amdgcn_logf(tg) - tg * sc);
            wsum += w[k];
        }
        float inv = 1.0f / wsum;
#pragma unroll
        for (int k = 0; k < LENF; ++k) w[k] *= inv;
#pragma unroll
        for (int j = 0; j < LENF - 1; ++j) r[j] = 0.0f;
    }

    // batch prefetch of one input block into a register buffer
    auto LOADIN = [&](F3* buf, int blk) {
#pragma unroll
        for (int i = 0; i < KB; ++i)
            buf[i] = xv[(size_t)(blk * KB + i) * NGRID + g];
    };
    // snow chain for one block (consumes a register buffer loaded last round)
    auto SNOW = [&](const F3* in, int b) {
        float2 (*rp)[64] = rtpe_buf[b & 1];
#pragma unroll
        for (int i = 0; i < KB; ++i) {
            float p = in[i].p, tm = in[i].t;
            float dt = tm - aTT;
            float rain = (dt >= 0.0f) ? p : 0.0f;
            float mm = fmaxf(aCFMAX * dt, 0.0f);
            float rr = fmaxf(-aCFRxCFMAX * dt, 0.0f);   // == aCFRxCFMAX*(aTT-tm)
            snow += p - rain;
            float mq = fminf(mm, snow);
            melt += mq; snow -= mq;
            float refr = fminf(rr, melt);
            snow += refr; melt -= refr;
            float tosoil = fmaxf(fmaf(-aCWH, snow, melt), 0.0f);
            melt -= tosoil;
            rp[i][lane] = make_float2(rain + tosoil, in[i].e);
        }
    };

    for (int m = 0; m < NROUND; ++m) {
        if (wid == 0) {
            // section A1: issue next block's 10 loads FIRST (old by barrier)
            if (m < NBLK) {
                if ((m & 1) == 0) LOADIN(abufA, m);
                else              LOADIN(abufB, m);
            }
            __builtin_amdgcn_sched_barrier(0);
            // section A2: snow chain on the block loaded LAST round
            if (m >= 1 && m <= NBLK) {
                int b = m - 1;
                if ((b & 1) == 0) SNOW(abufA, b);
                else              SNOW(abufB, b);
            }
        } else if (wid == 1) {
            if (m >= 2 && m <= NBLK + 1) {
                int b = m - 2, slot = b & 1;
                float rt[KB], pe[KB];
#pragma unroll
                for (int i = 0; i < KB; ++i) {
                    float2 v = rtpe_buf[slot][i][lane];
                    rt[i] = v.x; pe[i] = v.y;
                }
#pragma unroll
                for (int i = 0; i < KB; ++i) {
                    // soil_wet = clip((sm/FC)^BETA): ALU pow, chain ~60cy
                    float L1  = fast_log2_b(sm);
                    float sw  = fminf(fast_exp2(fmaf(bBETA, L1, bB1p)), 1.0f);
                    float smp = sm + rt[i];
                    float sm1 = fmaf(-rt[i], sw, smp);
                    float rch = rt[i] * sw;
                    float sm2 = fminf(sm1, bFC);
                    float exc = fmaxf(sm1 - bFC, 0.0f);
                    // evapfac = clip((sm2/(LP*FC))^BETAET)
                    float L2  = fast_log2_b(sm2);
                    float ef  = fminf(fast_exp2(fmaf(bBETAET, L2, bB2p)), 1.0f);
                    float sm3 = fmaxf(fmaf(-pe[i], ef, sm2), NEARZERO);
                    float d   = fmaxf(fmaf(-bInvFC, sm3, 1.0f), 0.0f);
                    float cz  = bC * slz;
                    float cap = fminf(slz, cz * d);
                    sm = sm3 + cap;
                    float slz1 = fmaxf(slz - cap, NEARZERO);
                    float su1 = suz + rch + exc;
                    float pa  = fminf(su1, bPERC);
                    float su2 = su1 - pa;
                    float q0  = bK0 * fmaxf(su2 - bUZL, 0.0f);
                    float su3 = su2 - q0;
                    float q1  = bK1 * su3;
                    suz = su3 - q1;
                    float sl2 = slz1 + pa;
                    float q2  = bK2 * sl2;
                    slz = sl2 - q2;
                    q_buf[slot][i][lane] = (q0 + q1) + q2;
                }
            }
        } else {
            // section C1: store LAST round's outputs first (old by barrier)
            if (m >= 4 && m <= NBLK + 3) {
                int bs = m - 4;
#pragma unroll
                for (int i = 0; i < KB; ++i)
                    out[(size_t)(bs * KB + i) * NGRID + g] = outv[i];
            }
            __builtin_amdgcn_sched_barrier(0);
            // section C2: FIR for block m-3 into the register out-buffer
            if (m >= 3 && m <= NBLK + 2) {
                int b = m - 3, slot = b & 1;
                float qv[KB];
#pragma unroll
                for (int i = 0; i < KB; ++i) qv[i] = q_buf[slot][i][lane];
#pragma unroll
                for (int i = 0; i < KB; ++i) {
                    float q = qv[i];
                    outv[i] = fmaf(w[0], q, r[0]);
#pragma unroll
                    for (int j = 0; j < LENF - 2; ++j)
                        r[j] = fmaf(w[j + 1], q, r[j + 1]);
                    r[LENF - 2] = w[LENF - 1] * q;
                }
            }
        }
        __syncthreads();
    }
}

extern "C" void kernel_launch(void* const* d_in, const int* in_sizes, int n_in,
                              void* d_out, int out_size, void* d_ws, size_t ws_size,
                              hipStream_t stream) {
    const float* x_phy      = (const float*)d_in[0]; // f32 (730,10000,3)
    const float* phy_static = (const float*)d_in[1]; // f32 (10000,16)
    float* out = (float*)d_out;                      // f32 (730,10000)

    int nwg = (NGRID + 63) / 64;  // 157 workgroups x 192 threads (3 waves)
    hbv_pipe3<<<nwg, 192, 0, stream>>>(x_phy, phy_static, out);
}